// Round 1
// baseline (31298.550 us; speedup 1.0000x reference)
//
#include <hip/hip_runtime.h>
#include <cstdint>
#include <cstddef>

#define NB 64
#define NT 600
#define NU 80
#define NV 60
#define CS 400
#define NK 10
#define NM 20
#define G4 1600      // 4*CS
#define K1 463       // 63 + 400  (lstm1: [x(3),w(60)] + h1(400))
#define K2 463       // 3+60+400  (lstm2 ih input dims)
#define NP 121       // 1 + 6*M
#define CAT 800      // 2*CS
#define CHUNK 75
#define NCHUNK 8

// d_out element offsets (concatenated return tuple)
#define OFF_END  0u
#define OFF_W    38400u
#define OFF_MU1  806400u
#define OFF_MU2  1574400u
#define OFF_LS1  2342400u
#define OFF_LS2  3110400u
#define OFF_RHO  3878400u
#define OFF_WOLD 4646400u
#define OFF_KAP  4650240u
#define OFF_H1   4650880u
#define OFF_C1   4676480u
#define OFF_H2   4702080u
#define OFF_C2   4727680u
#define OFF_PHI  4753280u

typedef unsigned short ush;

__device__ __forceinline__ float sigm(float v) { return 1.f / (1.f + expf(-v)); }
__device__ __forceinline__ float blo(unsigned u) { return __uint_as_float(u << 16); }
__device__ __forceinline__ float bhi(unsigned u) { return __uint_as_float(u & 0xffff0000u); }
__device__ __forceinline__ float b2f(ush v) { return __uint_as_float(((unsigned)v) << 16); }
__device__ __forceinline__ ush f2b(float f) {  // round-nearest-even
    unsigned u = __float_as_uint(f);
    unsigned r = (u + 0x7fffu + ((u >> 16) & 1u)) >> 16;
    return (ush)r;
}

// ---------------------------------------------------------------- prep
__global__ void prep_k(const float* __restrict__ W1ih, const float* __restrict__ W1hh,
                       const float* __restrict__ Ww, const float* __restrict__ W2ih,
                       const float* __restrict__ W2hh, const float* __restrict__ Wo,
                       float* __restrict__ W1T, ush* __restrict__ W2T,
                       float* __restrict__ WwT, ush* __restrict__ WoT) {
    int i = blockIdx.x * blockDim.x + threadIdx.x;
    if (i < K1 * G4) {  // W1T[k][j] fp32
        int k = i / G4, j = i % G4;
        W1T[i] = (k < 63) ? W1ih[j * 63 + k] : W1hh[j * CS + (k - 63)];
    }
    if (i < 863 * G4) {  // W2T[k][j] bf16 (k<463: ih, else hh)
        int k = i / G4, j = i % G4;
        float v = (k < K2) ? W2ih[j * K2 + k] : W2hh[j * CS + (k - K2)];
        W2T[i] = f2b(v);
    }
    if (i < CS * 30) {  // WwT[k][g] fp32
        int k = i / 30, g = i % 30;
        WwT[i] = Ww[g * CS + k];
    }
    if (i < CAT * NP) {  // WoT[k][j] bf16
        int k = i / NP, j = i % NP;
        WoT[i] = f2b(Wo[j * CAT + k]);
    }
}

// ---------------------------------------------------------------- scan1 (LSTM1 + attention), one block per batch
__global__ __launch_bounds__(1024) void scan1_k(
    const float* __restrict__ x, const float* __restrict__ onehots,
    const float* __restrict__ text_lens, const float* __restrict__ w0,
    const float* __restrict__ kap0, const float* __restrict__ h10,
    const float* __restrict__ c10, const float* __restrict__ b1,
    const float* __restrict__ bw, const float* __restrict__ W1T,
    const float* __restrict__ WwT,
    ush* __restrict__ h1s, ush* __restrict__ wsA, float* __restrict__ outp) {
    const int b = blockIdx.x, tid = threadIdx.x;
    __shared__ float inp[K1];          // [0:3]=x_t, [3:63]=w, [63:463]=h1
    __shared__ float cst[CS];
    __shared__ float part[5 * G4];
    __shared__ float oh[NU * NV];
    __shared__ float bias[G4];
    __shared__ float al[NK], be[NK], kap[NK], phi[NU + 1];
    __shared__ float tl;

    for (int i = tid; i < NU * NV; i += 1024) oh[i] = onehots[b * NU * NV + i];
    for (int i = tid; i < G4; i += 1024) bias[i] = b1[i];
    if (tid < CS) { inp[63 + tid] = h10[b * CS + tid]; cst[tid] = c10[b * CS + tid]; }
    if (tid < NV) inp[3 + tid] = w0[b * NV + tid];
    if (tid < NK) kap[tid] = kap0[b * NK + tid];
    if (tid < 3)  inp[tid] = x[(b * NT + 0) * 3 + tid];
    if (tid == 0) tl = text_lens[b];
    __syncthreads();

    for (int t = 0; t < NT; ++t) {
        // s1: gate partials — jt owns 8 consecutive j, ks owns a k-slice
        if (tid < 1000) {
            int ks = tid / 200, jt = tid - ks * 200;
            int k0 = ks * 93, k1 = (ks == 4) ? K1 : k0 + 93;
            float acc[8] = {0.f, 0.f, 0.f, 0.f, 0.f, 0.f, 0.f, 0.f};
            const float* wbase = W1T + jt * 8;
            for (int k = k0; k < k1; ++k) {
                float a = inp[k];
                const float* wr = wbase + (size_t)k * G4;
                float4 u = *(const float4*)(wr);
                float4 v = *(const float4*)(wr + 4);
                acc[0] = fmaf(a, u.x, acc[0]); acc[1] = fmaf(a, u.y, acc[1]);
                acc[2] = fmaf(a, u.z, acc[2]); acc[3] = fmaf(a, u.w, acc[3]);
                acc[4] = fmaf(a, v.x, acc[4]); acc[5] = fmaf(a, v.y, acc[5]);
                acc[6] = fmaf(a, v.z, acc[6]); acc[7] = fmaf(a, v.w, acc[7]);
            }
            float* pp = part + ks * G4 + jt * 8;
            #pragma unroll
            for (int r = 0; r < 8; ++r) pp[r] = acc[r];
        }
        __syncthreads();
        // s2: combine + LSTM cell
        if (tid < CS) {
            float gi = bias[tid], gf = bias[CS + tid], gg = bias[2 * CS + tid], go = bias[3 * CS + tid];
            #pragma unroll
            for (int ks = 0; ks < 5; ++ks) {
                const float* pp = part + ks * G4;
                gi += pp[tid]; gf += pp[CS + tid]; gg += pp[2 * CS + tid]; go += pp[3 * CS + tid];
            }
            float c = sigm(gf) * cst[tid] + sigm(gi) * tanhf(gg);
            float h = sigm(go) * tanhf(c);
            cst[tid] = c;
            inp[63 + tid] = h;
            h1s[((size_t)t * NB + b) * CS + tid] = f2b(h);
        }
        __syncthreads();
        // s3: p = exp(h1@Ww.T + bw); kappa update
        if (tid < 480) {
            int g = tid >> 4, l = tid & 15;
            float s = 0.f;
            for (int k = l; k < CS; k += 16) s += inp[63 + k] * WwT[k * 30 + g];
            s += __shfl_down(s, 8, 16);
            s += __shfl_down(s, 4, 16);
            s += __shfl_down(s, 2, 16);
            s += __shfl_down(s, 1, 16);
            if (l == 0) {
                float pv = expf(s + bw[g]);
                if (g < NK) al[g] = pv;
                else if (g < 2 * NK) be[g - NK] = pv;
                else kap[g - 2 * NK] += pv;
            }
        }
        __syncthreads();
        // s4: phi
        if (tid <= NU) {
            float u = (float)tid, s = 0.f;
            #pragma unroll
            for (int k = 0; k < NK; ++k) { float d = kap[k] - u; s += al[k] * expf(-be[k] * d * d); }
            phi[tid] = s * (80.f / tl);
        }
        __syncthreads();
        // s5: w + x prefetch
        if (tid < NV) {
            float s = 0.f;
            for (int u = 0; u < NU; ++u) s += phi[u] * oh[u * NV + tid];
            inp[3 + tid] = s;
            wsA[((size_t)t * NB + b) * NV + tid] = f2b(s);
        } else if (tid >= 64 && tid < 67) {
            if (t + 1 < NT) inp[tid - 64] = x[(b * NT + t + 1) * 3 + (tid - 64)];
        }
        __syncthreads();
    }
    if (tid < CS) { outp[OFF_H1 + b * CS + tid] = inp[63 + tid]; outp[OFF_C1 + b * CS + tid] = cst[tid]; }
    if (tid < NV) outp[OFF_WOLD + b * NV + tid] = inp[3 + tid];
    if (tid < NK) outp[OFF_KAP + b * NK + tid] = kap[tid];
    if (tid <= NU) outp[OFF_PHI + b * (NU + 1) + tid] = phi[tid];
}

// ---------------------------------------------------------------- Z = lstm2_in @ W2_ih.T + b2  (chunked GEMM)
__global__ __launch_bounds__(256) void gemmZ_k(
    const float* __restrict__ x, const ush* __restrict__ wsA, const ush* __restrict__ h1s,
    const ush* __restrict__ W2T, const float* __restrict__ b2,
    ush* __restrict__ Z, int n0) {
    __shared__ float As[32][64];
    __shared__ float Bs[32][64];
    const int tid = threadIdx.x;
    const int jt = blockIdx.x * 64;
    const int nt = blockIdx.y * 64;   // chunk-relative n'
    const int tx = tid & 15, ty = tid >> 4;
    float acc[4][4] = {};
    for (int k0 = 0; k0 < K2; k0 += 32) {
        {   // A tile (gather): n' = t*64 + b ordering
            int n = tid >> 2, kk = (tid & 3) * 8;
            int np = n0 + nt + n;
            int bb = np & 63, tt = np >> 6;
            #pragma unroll
            for (int r = 0; r < 8; ++r) {
                int k = k0 + kk + r;
                float v = 0.f;
                if (k < K2) {
                    if (k < 3) v = x[(bb * NT + tt) * 3 + k];
                    else if (k < 63) v = b2f(wsA[((size_t)tt * NB + bb) * NV + (k - 3)]);
                    else v = b2f(h1s[((size_t)tt * NB + bb) * CS + (k - 63)]);
                }
                As[kk + r][n] = v;
            }
        }
        {   // B tile
            int kk = tid >> 3, j8 = (tid & 7) * 8;
            int k = k0 + kk;
            if (k < K2) {
                uint4 wv = *(const uint4*)(W2T + (size_t)k * G4 + jt + j8);
                Bs[kk][j8 + 0] = blo(wv.x); Bs[kk][j8 + 1] = bhi(wv.x);
                Bs[kk][j8 + 2] = blo(wv.y); Bs[kk][j8 + 3] = bhi(wv.y);
                Bs[kk][j8 + 4] = blo(wv.z); Bs[kk][j8 + 5] = bhi(wv.z);
                Bs[kk][j8 + 6] = blo(wv.w); Bs[kk][j8 + 7] = bhi(wv.w);
            } else {
                #pragma unroll
                for (int r = 0; r < 8; ++r) Bs[kk][j8 + r] = 0.f;
            }
        }
        __syncthreads();
        #pragma unroll
        for (int kk = 0; kk < 32; ++kk) {
            float a0 = As[kk][ty * 4 + 0], a1 = As[kk][ty * 4 + 1];
            float a2 = As[kk][ty * 4 + 2], a3 = As[kk][ty * 4 + 3];
            float c0 = Bs[kk][tx * 4 + 0], c1 = Bs[kk][tx * 4 + 1];
            float c2 = Bs[kk][tx * 4 + 2], c3 = Bs[kk][tx * 4 + 3];
            acc[0][0] = fmaf(a0, c0, acc[0][0]); acc[0][1] = fmaf(a0, c1, acc[0][1]);
            acc[0][2] = fmaf(a0, c2, acc[0][2]); acc[0][3] = fmaf(a0, c3, acc[0][3]);
            acc[1][0] = fmaf(a1, c0, acc[1][0]); acc[1][1] = fmaf(a1, c1, acc[1][1]);
            acc[1][2] = fmaf(a1, c2, acc[1][2]); acc[1][3] = fmaf(a1, c3, acc[1][3]);
            acc[2][0] = fmaf(a2, c0, acc[2][0]); acc[2][1] = fmaf(a2, c1, acc[2][1]);
            acc[2][2] = fmaf(a2, c2, acc[2][2]); acc[2][3] = fmaf(a2, c3, acc[2][3]);
            acc[3][0] = fmaf(a3, c0, acc[3][0]); acc[3][1] = fmaf(a3, c1, acc[3][1]);
            acc[3][2] = fmaf(a3, c2, acc[3][2]); acc[3][3] = fmaf(a3, c3, acc[3][3]);
        }
        __syncthreads();
    }
    #pragma unroll
    for (int r = 0; r < 4; ++r) {
        int n = nt + ty * 4 + r;
        #pragma unroll
        for (int c = 0; c < 4; ++c) {
            int j = jt + tx * 4 + c;
            Z[(size_t)n * G4 + j] = f2b(acc[r][c] + b2[j]);
        }
    }
}

// ---------------------------------------------------------------- scan2 (LSTM2 + fused MDN head), one block per batch
__global__ __launch_bounds__(1024) void scan2_k(
    const ush* __restrict__ Z, const ush* __restrict__ W2T, const ush* __restrict__ WoT,
    const ush* __restrict__ h1s, const float* __restrict__ bo,
    const float* __restrict__ h20, const float* __restrict__ c20,
    float* __restrict__ h2st, float* __restrict__ c2st,
    float* __restrict__ outp, int t0, int first, int last) {
    const int b = blockIdx.x, tid = threadIdx.x;
    __shared__ float hl[CS], cl[CS], h1f[CS];
    __shared__ float part[5 * G4];
    __shared__ float params[NP];
    __shared__ float bol[NP];
    if (tid < CS) {
        hl[tid] = first ? h20[b * CS + tid] : h2st[b * CS + tid];
        cl[tid] = first ? c20[b * CS + tid] : c2st[b * CS + tid];
    }
    if (tid < NP) bol[tid] = bo[tid];
    __syncthreads();
    for (int ti = 0; ti < CHUNK; ++ti) {
        const int t = t0 + ti;
        // s1: hh gate partials
        if (tid < 1000) {
            int ks = tid / 200, jt = tid - ks * 200;
            int k0 = ks * 80, k1 = k0 + 80;
            float acc[8] = {0.f, 0.f, 0.f, 0.f, 0.f, 0.f, 0.f, 0.f};
            const ush* wb = W2T + (size_t)K2 * G4 + jt * 8;
            for (int k = k0; k < k1; ++k) {
                float a = hl[k];
                uint4 wv = *(const uint4*)(wb + (size_t)k * G4);
                acc[0] = fmaf(a, blo(wv.x), acc[0]); acc[1] = fmaf(a, bhi(wv.x), acc[1]);
                acc[2] = fmaf(a, blo(wv.y), acc[2]); acc[3] = fmaf(a, bhi(wv.y), acc[3]);
                acc[4] = fmaf(a, blo(wv.z), acc[4]); acc[5] = fmaf(a, bhi(wv.z), acc[5]);
                acc[6] = fmaf(a, blo(wv.w), acc[6]); acc[7] = fmaf(a, bhi(wv.w), acc[7]);
            }
            float* pp = part + ks * G4 + jt * 8;
            #pragma unroll
            for (int r = 0; r < 8; ++r) pp[r] = acc[r];
        }
        if (tid < CS) h1f[tid] = b2f(h1s[((size_t)t * NB + b) * CS + tid]);
        __syncthreads();
        // s2: combine + cell
        if (tid < CS) {
            const size_t zb = ((size_t)ti * NB + b) * G4;
            float gi = b2f(Z[zb + tid]);
            float gf = b2f(Z[zb + CS + tid]);
            float gg = b2f(Z[zb + 2 * CS + tid]);
            float go = b2f(Z[zb + 3 * CS + tid]);
            #pragma unroll
            for (int ks = 0; ks < 5; ++ks) {
                const float* pp = part + ks * G4;
                gi += pp[tid]; gf += pp[CS + tid]; gg += pp[2 * CS + tid]; go += pp[3 * CS + tid];
            }
            float c = sigm(gf) * cl[tid] + sigm(gi) * tanhf(gg);
            float h = sigm(go) * tanhf(c);
            cl[tid] = c; hl[tid] = h;
        }
        __syncthreads();
        // s3: params = [h1,h2]@Wo.T + bo
        if (tid < 968) {
            int j = tid >> 3, l = tid & 7;
            int k0 = l * 100;
            float s = 0.f;
            for (int k = k0; k < k0 + 100; ++k) {
                float cv = (k < CS) ? h1f[k] : hl[k - CS];
                s += cv * b2f(WoT[k * NP + j]);
            }
            s += __shfl_down(s, 4, 8);
            s += __shfl_down(s, 2, 8);
            s += __shfl_down(s, 1, 8);
            if (l == 0) params[j] = s + bol[j];
        }
        __syncthreads();
        // s4: MDN head
        {
            const size_t nt_ = (size_t)b * NT + t;
            if (tid < NM) {
                float mx = -1e30f;
                for (int m = 0; m < NM; ++m) mx = fmaxf(mx, params[m]);
                float sm = 0.f;
                for (int m = 0; m < NM; ++m) sm += expf(params[m] - mx);
                outp[OFF_W   + nt_ * NM + tid] = expf(params[tid] - mx) / sm;
                outp[OFF_MU1 + nt_ * NM + tid] = params[NM + tid];
                outp[OFF_MU2 + nt_ * NM + tid] = params[2 * NM + tid];
                outp[OFF_LS1 + nt_ * NM + tid] = params[3 * NM + tid];
                outp[OFF_LS2 + nt_ * NM + tid] = params[4 * NM + tid];
                outp[OFF_RHO + nt_ * NM + tid] = tanhf(params[5 * NM + tid]);
            } else if (tid == 64) {
                outp[OFF_END + nt_] = sigm(params[6 * NM]);
            }
        }
        __syncthreads();
    }
    if (tid < CS) {
        h2st[b * CS + tid] = hl[tid];
        c2st[b * CS + tid] = cl[tid];
        if (last) { outp[OFF_H2 + b * CS + tid] = hl[tid]; outp[OFF_C2 + b * CS + tid] = cl[tid]; }
    }
}

// ---------------------------------------------------------------- launch
extern "C" void kernel_launch(void* const* d_in, const int* in_sizes, int n_in,
                              void* d_out, int out_size, void* d_ws, size_t ws_size,
                              hipStream_t stream) {
    const float* x    = (const float*)d_in[0];
    const float* oh   = (const float*)d_in[1];
    const float* tl   = (const float*)d_in[2];
    const float* w0   = (const float*)d_in[3];
    const float* kp0  = (const float*)d_in[4];
    const float* h10  = (const float*)d_in[5];
    const float* c10  = (const float*)d_in[6];
    const float* h20  = (const float*)d_in[7];
    const float* c20  = (const float*)d_in[8];
    const float* W1ih = (const float*)d_in[9];
    const float* W1hh = (const float*)d_in[10];
    const float* b1   = (const float*)d_in[11];
    const float* Ww   = (const float*)d_in[12];
    const float* bw   = (const float*)d_in[13];
    const float* W2ih = (const float*)d_in[14];
    const float* W2hh = (const float*)d_in[15];
    const float* b2   = (const float*)d_in[16];
    const float* Wo   = (const float*)d_in[17];
    const float* bo   = (const float*)d_in[18];
    float* outp = (float*)d_out;

    char* p = (char*)d_ws;
    auto alloc = [&](size_t bytes) { char* r = p; p += (bytes + 255) & ~(size_t)255; return r; };
    float* W1T  = (float*)alloc((size_t)K1 * G4 * 4);
    ush*   W2T  = (ush*)  alloc((size_t)863 * G4 * 2);
    float* WwT  = (float*)alloc((size_t)CS * 30 * 4);
    ush*   WoT  = (ush*)  alloc((size_t)CAT * NP * 2);
    ush*   h1s  = (ush*)  alloc((size_t)NT * NB * CS * 2);
    ush*   wsA  = (ush*)  alloc((size_t)NT * NB * NV * 2);
    ush*   Zb   = (ush*)  alloc((size_t)CHUNK * NB * G4 * 2);
    float* h2st = (float*)alloc((size_t)NB * CS * 4);
    float* c2st = (float*)alloc((size_t)NB * CS * 4);

    prep_k<<<(863 * G4 + 255) / 256, 256, 0, stream>>>(W1ih, W1hh, Ww, W2ih, W2hh, Wo,
                                                       W1T, W2T, WwT, WoT);
    scan1_k<<<NB, 1024, 0, stream>>>(x, oh, tl, w0, kp0, h10, c10, b1, bw, W1T, WwT,
                                     h1s, wsA, outp);
    for (int c = 0; c < NCHUNK; ++c) {
        gemmZ_k<<<dim3(G4 / 64, CHUNK * NB / 64), 256, 0, stream>>>(
            x, wsA, h1s, W2T, b2, Zb, c * CHUNK * NB);
        scan2_k<<<NB, 1024, 0, stream>>>(
            Zb, W2T, WoT, h1s, bo, h20, c20, h2st, c2st, outp,
            c * CHUNK, c == 0, c == NCHUNK - 1);
    }
}

// Round 2
// 21912.103 us; speedup vs baseline: 1.4284x; 1.4284x over previous
//
#include <hip/hip_runtime.h>
#include <cstdint>
#include <cstddef>

#define NB 64
#define NT 600
#define NU 80
#define NV 60
#define CS 400
#define NK 10
#define NM 20
#define G4 1600      // 4*CS
#define K1 463       // 63 + 400  (lstm1: [x(3),w(60)] + h1(400))
#define K2 463       // 3+60+400  (lstm2 ih input dims)
#define NP 121       // 1 + 6*M
#define CAT 800      // 2*CS
#define CHUNK 75
#define NCHUNK 8

// d_out element offsets (concatenated return tuple)
#define OFF_END  0u
#define OFF_W    38400u
#define OFF_MU1  806400u
#define OFF_MU2  1574400u
#define OFF_LS1  2342400u
#define OFF_LS2  3110400u
#define OFF_RHO  3878400u
#define OFF_WOLD 4646400u
#define OFF_KAP  4650240u
#define OFF_H1   4650880u
#define OFF_C1   4676480u
#define OFF_H2   4702080u
#define OFF_C2   4727680u
#define OFF_PHI  4753280u

typedef unsigned short ush;

__device__ __forceinline__ float sigm(float v) { return 1.f / (1.f + expf(-v)); }
__device__ __forceinline__ float blo(unsigned u) { return __uint_as_float(u << 16); }
__device__ __forceinline__ float bhi(unsigned u) { return __uint_as_float(u & 0xffff0000u); }
__device__ __forceinline__ float b2f(ush v) { return __uint_as_float(((unsigned)v) << 16); }
__device__ __forceinline__ ush f2b(float f) {  // round-nearest-even
    unsigned u = __float_as_uint(f);
    unsigned r = (u + 0x7fffu + ((u >> 16) & 1u)) >> 16;
    return (ush)r;
}

// ---------------------------------------------------------------- prep
__global__ void prep_k(const float* __restrict__ W1ih, const float* __restrict__ W1hh,
                       const float* __restrict__ W2ih, const float* __restrict__ W2hh,
                       const float* __restrict__ Wo,
                       ush* __restrict__ W1T, ush* __restrict__ W2T,
                       ush* __restrict__ WoB) {
    int i = blockIdx.x * blockDim.x + threadIdx.x;
    if (i < K1 * G4) {  // W1T[k][j] bf16
        int k = i / G4, j = i % G4;
        float v = (k < 63) ? W1ih[j * 63 + k] : W1hh[j * CS + (k - 63)];
        W1T[i] = f2b(v);
    }
    if (i < 863 * G4) {  // W2T[k][j] bf16 (k<463: ih, else hh)
        int k = i / G4, j = i % G4;
        float v = (k < K2) ? W2ih[j * K2 + k] : W2hh[j * CS + (k - K2)];
        W2T[i] = f2b(v);
    }
    if (i < NP * CAT) {  // WoB[j][k] bf16 (same layout as Wo)
        WoB[i] = f2b(Wo[i]);
    }
}

// ---------------------------------------------------------------- scan1 (LSTM1 + attention), one block per batch
__global__ __launch_bounds__(1024) void scan1_k(
    const float* __restrict__ x, const float* __restrict__ onehots,
    const float* __restrict__ text_lens, const float* __restrict__ w0,
    const float* __restrict__ kap0, const float* __restrict__ h10,
    const float* __restrict__ c10, const float* __restrict__ b1,
    const float* __restrict__ Ww, const float* __restrict__ bw,
    const ush* __restrict__ W1T,
    ush* __restrict__ h1s, ush* __restrict__ wsA, float* __restrict__ outp) {
    const int b = blockIdx.x, tid = threadIdx.x;
    __shared__ float inp[K1];          // [0:3]=x_t, [3:63]=w, [63:463]=h1
    __shared__ float cst[CS];
    __shared__ float part[5 * G4];     // transposed: [(ks*8+r)*200 + jt]
    __shared__ float oh[NU * NV];
    __shared__ float bias[G4];
    __shared__ float al[NK], be[NK], kap[NK], phi[NU + 1];
    __shared__ float bwl[3 * NK];
    __shared__ float tl;

    for (int i = tid; i < NU * NV; i += 1024) oh[i] = onehots[b * NU * NV + i];
    for (int i = tid; i < G4; i += 1024) bias[i] = b1[i];
    if (tid < CS) { inp[63 + tid] = h10[b * CS + tid]; cst[tid] = c10[b * CS + tid]; }
    if (tid < NV) inp[3 + tid] = w0[b * NV + tid];
    if (tid < NK) kap[tid] = kap0[b * NK + tid];
    if (tid < 3)  inp[tid] = x[(b * NT + 0) * 3 + tid];
    if (tid >= 32 && tid < 62) bwl[tid - 32] = bw[tid - 32];
    if (tid == 0) tl = text_lens[b];
    __syncthreads();

    for (int t = 0; t < NT; ++t) {
        // s1: gate partials — jt owns 8 consecutive j, ks owns a k-slice
        if (tid < 1000) {
            int ks = tid / 200, jt = tid - ks * 200;
            int k0 = ks * 93, k1 = (ks == 4) ? K1 : k0 + 93;
            float acc[8] = {0.f, 0.f, 0.f, 0.f, 0.f, 0.f, 0.f, 0.f};
            const ush* wb = W1T + jt * 8;
            for (int k = k0; k < k1; ++k) {
                float a = inp[k];
                uint4 wv = *(const uint4*)(wb + (size_t)k * G4);
                acc[0] = fmaf(a, blo(wv.x), acc[0]); acc[1] = fmaf(a, bhi(wv.x), acc[1]);
                acc[2] = fmaf(a, blo(wv.y), acc[2]); acc[3] = fmaf(a, bhi(wv.y), acc[3]);
                acc[4] = fmaf(a, blo(wv.z), acc[4]); acc[5] = fmaf(a, bhi(wv.z), acc[5]);
                acc[6] = fmaf(a, blo(wv.w), acc[6]); acc[7] = fmaf(a, bhi(wv.w), acc[7]);
            }
            float* pp = part + ks * G4 + jt;
            #pragma unroll
            for (int r = 0; r < 8; ++r) pp[r * 200] = acc[r];
        }
        __syncthreads();
        // s2: combine + LSTM cell
        if (tid < CS) {
            float gi = bias[tid], gf = bias[CS + tid], gg = bias[2 * CS + tid], go = bias[3 * CS + tid];
            #pragma unroll
            for (int ks = 0; ks < 5; ++ks) {
                const float* pp = part + ks * G4 + (tid & 7) * 200 + (tid >> 3);
                gi += pp[0]; gf += pp[50]; gg += pp[100]; go += pp[150];
            }
            float c = sigm(gf) * cst[tid] + sigm(gi) * tanhf(gg);
            float h = sigm(go) * tanhf(c);
            cst[tid] = c;
            inp[63 + tid] = h;
            h1s[((size_t)t * NB + b) * CS + tid] = f2b(h);
        }
        __syncthreads();
        // s3: p = exp(h1@Ww.T + bw); kappa update
        if (tid < 480) {
            int g = tid >> 4, l = tid & 15;
            float s = 0.f;
            const float* wr = Ww + g * CS;
            for (int k = l; k < CS; k += 16) s += inp[63 + k] * wr[k];
            s += __shfl_down(s, 8, 16);
            s += __shfl_down(s, 4, 16);
            s += __shfl_down(s, 2, 16);
            s += __shfl_down(s, 1, 16);
            if (l == 0) {
                float pv = expf(s + bwl[g]);
                if (g < NK) al[g] = pv;
                else if (g < 2 * NK) be[g - NK] = pv;
                else kap[g - 2 * NK] += pv;
            }
        }
        __syncthreads();
        // s4: phi
        if (tid <= NU) {
            float u = (float)tid, s = 0.f;
            #pragma unroll
            for (int k = 0; k < NK; ++k) { float d = kap[k] - u; s += al[k] * expf(-be[k] * d * d); }
            phi[tid] = s * (80.f / tl);
        }
        __syncthreads();
        // s5: w + x prefetch
        if (tid < NV) {
            float s = 0.f;
            for (int u = 0; u < NU; ++u) s += phi[u] * oh[u * NV + tid];
            inp[3 + tid] = s;
            wsA[((size_t)t * NB + b) * NV + tid] = f2b(s);
        } else if (tid >= 64 && tid < 67) {
            if (t + 1 < NT) inp[tid - 64] = x[(b * NT + t + 1) * 3 + (tid - 64)];
        }
        __syncthreads();
    }
    if (tid < CS) { outp[OFF_H1 + b * CS + tid] = inp[63 + tid]; outp[OFF_C1 + b * CS + tid] = cst[tid]; }
    if (tid < NV) outp[OFF_WOLD + b * NV + tid] = inp[3 + tid];
    if (tid < NK) outp[OFF_KAP + b * NK + tid] = kap[tid];
    if (tid <= NU) outp[OFF_PHI + b * (NU + 1) + tid] = phi[tid];
}

// ---------------------------------------------------------------- Z = lstm2_in @ W2_ih.T + b2  (chunked GEMM)
__global__ __launch_bounds__(256) void gemmZ_k(
    const float* __restrict__ x, const ush* __restrict__ wsA, const ush* __restrict__ h1s,
    const ush* __restrict__ W2T, const float* __restrict__ b2,
    ush* __restrict__ Z, int n0) {
    __shared__ float As[32][64];
    __shared__ float Bs[32][64];
    const int tid = threadIdx.x;
    const int jt = blockIdx.x * 64;
    const int nt = blockIdx.y * 64;   // chunk-relative n'
    const int tx = tid & 15, ty = tid >> 4;
    float acc[4][4] = {};
    for (int k0 = 0; k0 < K2; k0 += 32) {
        {   // A tile (gather): n' = t*64 + b ordering
            int n = tid >> 2, kk = (tid & 3) * 8;
            int np = n0 + nt + n;
            int bb = np & 63, tt = np >> 6;
            #pragma unroll
            for (int r = 0; r < 8; ++r) {
                int k = k0 + kk + r;
                float v = 0.f;
                if (k < K2) {
                    if (k < 3) v = x[(bb * NT + tt) * 3 + k];
                    else if (k < 63) v = b2f(wsA[((size_t)tt * NB + bb) * NV + (k - 3)]);
                    else v = b2f(h1s[((size_t)tt * NB + bb) * CS + (k - 63)]);
                }
                As[kk + r][n] = v;
            }
        }
        {   // B tile
            int kk = tid >> 3, j8 = (tid & 7) * 8;
            int k = k0 + kk;
            if (k < K2) {
                uint4 wv = *(const uint4*)(W2T + (size_t)k * G4 + jt + j8);
                Bs[kk][j8 + 0] = blo(wv.x); Bs[kk][j8 + 1] = bhi(wv.x);
                Bs[kk][j8 + 2] = blo(wv.y); Bs[kk][j8 + 3] = bhi(wv.y);
                Bs[kk][j8 + 4] = blo(wv.z); Bs[kk][j8 + 5] = bhi(wv.z);
                Bs[kk][j8 + 6] = blo(wv.w); Bs[kk][j8 + 7] = bhi(wv.w);
            } else {
                #pragma unroll
                for (int r = 0; r < 8; ++r) Bs[kk][j8 + r] = 0.f;
            }
        }
        __syncthreads();
        #pragma unroll
        for (int kk = 0; kk < 32; ++kk) {
            float a0 = As[kk][ty * 4 + 0], a1 = As[kk][ty * 4 + 1];
            float a2 = As[kk][ty * 4 + 2], a3 = As[kk][ty * 4 + 3];
            float c0 = Bs[kk][tx * 4 + 0], c1 = Bs[kk][tx * 4 + 1];
            float c2 = Bs[kk][tx * 4 + 2], c3 = Bs[kk][tx * 4 + 3];
            acc[0][0] = fmaf(a0, c0, acc[0][0]); acc[0][1] = fmaf(a0, c1, acc[0][1]);
            acc[0][2] = fmaf(a0, c2, acc[0][2]); acc[0][3] = fmaf(a0, c3, acc[0][3]);
            acc[1][0] = fmaf(a1, c0, acc[1][0]); acc[1][1] = fmaf(a1, c1, acc[1][1]);
            acc[1][2] = fmaf(a1, c2, acc[1][2]); acc[1][3] = fmaf(a1, c3, acc[1][3]);
            acc[2][0] = fmaf(a2, c0, acc[2][0]); acc[2][1] = fmaf(a2, c1, acc[2][1]);
            acc[2][2] = fmaf(a2, c2, acc[2][2]); acc[2][3] = fmaf(a2, c3, acc[2][3]);
            acc[3][0] = fmaf(a3, c0, acc[3][0]); acc[3][1] = fmaf(a3, c1, acc[3][1]);
            acc[3][2] = fmaf(a3, c2, acc[3][2]); acc[3][3] = fmaf(a3, c3, acc[3][3]);
        }
        __syncthreads();
    }
    #pragma unroll
    for (int r = 0; r < 4; ++r) {
        int n = nt + ty * 4 + r;
        #pragma unroll
        for (int c = 0; c < 4; ++c) {
            int j = jt + tx * 4 + c;
            Z[(size_t)n * G4 + j] = f2b(acc[r][c] + b2[j]);
        }
    }
}

// ---------------------------------------------------------------- scan2 (LSTM2 + fused MDN head), one block per batch
__global__ __launch_bounds__(1024) void scan2_k(
    const ush* __restrict__ Z, const ush* __restrict__ W2T, const ush* __restrict__ WoB,
    const ush* __restrict__ h1s, const float* __restrict__ bo,
    const float* __restrict__ h20, const float* __restrict__ c20,
    float* __restrict__ h2st, float* __restrict__ c2st,
    float* __restrict__ outp, int t0, int first, int last) {
    const int b = blockIdx.x, tid = threadIdx.x;
    __shared__ float hl[CS], cl[CS];
    __shared__ float cat[CAT];         // [0:400]=h1_t, [400:800]=h2_t
    __shared__ float part[5 * G4];     // transposed
    __shared__ float params[NP];
    __shared__ float bol[NP];
    if (tid < CS) {
        hl[tid] = first ? h20[b * CS + tid] : h2st[b * CS + tid];
        cl[tid] = first ? c20[b * CS + tid] : c2st[b * CS + tid];
    }
    if (tid < NP) bol[tid] = bo[tid];
    __syncthreads();
    for (int ti = 0; ti < CHUNK; ++ti) {
        const int t = t0 + ti;
        // s1: hh gate partials
        if (tid < 1000) {
            int ks = tid / 200, jt = tid - ks * 200;
            int k0 = ks * 80, k1 = k0 + 80;
            float acc[8] = {0.f, 0.f, 0.f, 0.f, 0.f, 0.f, 0.f, 0.f};
            const ush* wb = W2T + (size_t)K2 * G4 + jt * 8;
            for (int k = k0; k < k1; ++k) {
                float a = hl[k];
                uint4 wv = *(const uint4*)(wb + (size_t)k * G4);
                acc[0] = fmaf(a, blo(wv.x), acc[0]); acc[1] = fmaf(a, bhi(wv.x), acc[1]);
                acc[2] = fmaf(a, blo(wv.y), acc[2]); acc[3] = fmaf(a, bhi(wv.y), acc[3]);
                acc[4] = fmaf(a, blo(wv.z), acc[4]); acc[5] = fmaf(a, bhi(wv.z), acc[5]);
                acc[6] = fmaf(a, blo(wv.w), acc[6]); acc[7] = fmaf(a, bhi(wv.w), acc[7]);
            }
            float* pp = part + ks * G4 + jt;
            #pragma unroll
            for (int r = 0; r < 8; ++r) pp[r * 200] = acc[r];
        }
        if (tid < CS) cat[tid] = b2f(h1s[((size_t)t * NB + b) * CS + tid]);
        __syncthreads();
        // s2: combine + cell
        if (tid < CS) {
            const size_t zb = ((size_t)ti * NB + b) * G4;
            float gi = b2f(Z[zb + tid]);
            float gf = b2f(Z[zb + CS + tid]);
            float gg = b2f(Z[zb + 2 * CS + tid]);
            float go = b2f(Z[zb + 3 * CS + tid]);
            #pragma unroll
            for (int ks = 0; ks < 5; ++ks) {
                const float* pp = part + ks * G4 + (tid & 7) * 200 + (tid >> 3);
                gi += pp[0]; gf += pp[50]; gg += pp[100]; go += pp[150];
            }
            float c = sigm(gf) * cl[tid] + sigm(gi) * tanhf(gg);
            float h = sigm(go) * tanhf(c);
            cl[tid] = c; hl[tid] = h;
            cat[CS + tid] = h;
        }
        __syncthreads();
        // s3: params = [h1,h2]@Wo.T + bo
        if (tid < 968) {
            int j = tid >> 3, l = tid & 7;
            const ush* wrow = WoB + j * CAT + l * 100;
            const float* crow = cat + l * 100;
            float s = 0.f;
            #pragma unroll 10
            for (int kk = 0; kk < 100; kk += 2) {
                unsigned wv = *(const unsigned*)(wrow + kk);
                s = fmaf(crow[kk], blo(wv), s);
                s = fmaf(crow[kk + 1], bhi(wv), s);
            }
            s += __shfl_down(s, 4, 8);
            s += __shfl_down(s, 2, 8);
            s += __shfl_down(s, 1, 8);
            if (l == 0) params[j] = s + bol[j];
        }
        __syncthreads();
        // s4: MDN head
        {
            const size_t nt_ = (size_t)b * NT + t;
            if (tid < NM) {
                float mx = -1e30f;
                for (int m = 0; m < NM; ++m) mx = fmaxf(mx, params[m]);
                float sm = 0.f;
                for (int m = 0; m < NM; ++m) sm += expf(params[m] - mx);
                outp[OFF_W   + nt_ * NM + tid] = expf(params[tid] - mx) / sm;
                outp[OFF_MU1 + nt_ * NM + tid] = params[NM + tid];
                outp[OFF_MU2 + nt_ * NM + tid] = params[2 * NM + tid];
                outp[OFF_LS1 + nt_ * NM + tid] = params[3 * NM + tid];
                outp[OFF_LS2 + nt_ * NM + tid] = params[4 * NM + tid];
                outp[OFF_RHO + nt_ * NM + tid] = tanhf(params[5 * NM + tid]);
            } else if (tid == 64) {
                outp[OFF_END + nt_] = sigm(params[6 * NM]);
            }
        }
        __syncthreads();
    }
    if (tid < CS) {
        h2st[b * CS + tid] = hl[tid];
        c2st[b * CS + tid] = cl[tid];
        if (last) { outp[OFF_H2 + b * CS + tid] = hl[tid]; outp[OFF_C2 + b * CS + tid] = cl[tid]; }
    }
}

// ---------------------------------------------------------------- launch
extern "C" void kernel_launch(void* const* d_in, const int* in_sizes, int n_in,
                              void* d_out, int out_size, void* d_ws, size_t ws_size,
                              hipStream_t stream) {
    const float* x    = (const float*)d_in[0];
    const float* oh   = (const float*)d_in[1];
    const float* tl   = (const float*)d_in[2];
    const float* w0   = (const float*)d_in[3];
    const float* kp0  = (const float*)d_in[4];
    const float* h10  = (const float*)d_in[5];
    const float* c10  = (const float*)d_in[6];
    const float* h20  = (const float*)d_in[7];
    const float* c20  = (const float*)d_in[8];
    const float* W1ih = (const float*)d_in[9];
    const float* W1hh = (const float*)d_in[10];
    const float* b1   = (const float*)d_in[11];
    const float* Ww   = (const float*)d_in[12];
    const float* bw   = (const float*)d_in[13];
    const float* W2ih = (const float*)d_in[14];
    const float* W2hh = (const float*)d_in[15];
    const float* b2   = (const float*)d_in[16];
    const float* Wo   = (const float*)d_in[17];
    const float* bo   = (const float*)d_in[18];
    float* outp = (float*)d_out;

    char* p = (char*)d_ws;
    auto alloc = [&](size_t bytes) { char* r = p; p += (bytes + 255) & ~(size_t)255; return r; };
    ush*   W1T  = (ush*)  alloc((size_t)K1 * G4 * 2);
    ush*   W2T  = (ush*)  alloc((size_t)863 * G4 * 2);
    ush*   WoB  = (ush*)  alloc((size_t)NP * CAT * 2);
    ush*   h1s  = (ush*)  alloc((size_t)NT * NB * CS * 2);
    ush*   wsA  = (ush*)  alloc((size_t)NT * NB * NV * 2);
    ush*   Zb   = (ush*)  alloc((size_t)CHUNK * NB * G4 * 2);
    float* h2st = (float*)alloc((size_t)NB * CS * 4);
    float* c2st = (float*)alloc((size_t)NB * CS * 4);

    prep_k<<<(863 * G4 + 255) / 256, 256, 0, stream>>>(W1ih, W1hh, W2ih, W2hh, Wo,
                                                       W1T, W2T, WoB);
    scan1_k<<<NB, 1024, 0, stream>>>(x, oh, tl, w0, kp0, h10, c10, b1, Ww, bw, W1T,
                                     h1s, wsA, outp);
    for (int c = 0; c < NCHUNK; ++c) {
        gemmZ_k<<<dim3(G4 / 64, CHUNK * NB / 64), 256, 0, stream>>>(
            x, wsA, h1s, W2T, b2, Zb, c * CHUNK * NB);
        scan2_k<<<NB, 1024, 0, stream>>>(
            Zb, W2T, WoB, h1s, bo, h20, c20, h2st, c2st, outp,
            c * CHUNK, c == 0, c == NCHUNK - 1);
    }
}

// Round 3
// 16437.717 us; speedup vs baseline: 1.9041x; 1.3330x over previous
//
#include <hip/hip_runtime.h>
#include <cstdint>
#include <cstddef>

#define NB 64
#define NT 600
#define NU 80
#define NV 60
#define CS 400
#define NK 10
#define NM 20
#define G4 1600      // 4*CS
#define K1 463       // 63 + 400
#define K2 463
#define NP 121
#define CAT 800
#define CHUNK 75
#define NCHUNK 8

#define OFF_END  0u
#define OFF_W    38400u
#define OFF_MU1  806400u
#define OFF_MU2  1574400u
#define OFF_LS1  2342400u
#define OFF_LS2  3110400u
#define OFF_RHO  3878400u
#define OFF_WOLD 4646400u
#define OFF_KAP  4650240u
#define OFF_H1   4650880u
#define OFF_C1   4676480u
#define OFF_H2   4702080u
#define OFF_C2   4727680u
#define OFF_PHI  4753280u

typedef unsigned short ush;

__device__ __forceinline__ float sigm(float v) { return 1.f / (1.f + expf(-v)); }
__device__ __forceinline__ float blo(unsigned u) { return __uint_as_float(u << 16); }
__device__ __forceinline__ float bhi(unsigned u) { return __uint_as_float(u & 0xffff0000u); }
__device__ __forceinline__ float b2f(ush v) { return __uint_as_float(((unsigned)v) << 16); }
__device__ __forceinline__ ush f2b(float f) {
    unsigned u = __float_as_uint(f);
    unsigned r = (u + 0x7fffu + ((u >> 16) & 1u)) >> 16;
    return (ush)r;
}

// ---------------------------------------------------------------- prep
// W1P: [k][jn] bf16 with jn = r*400 + g*100 + cl  <->  orig j = g*400 + r*100 + cl
// W2T: rows 0..462 = ih in ORIGINAL j layout (gemmZ), rows 463..862 = hh PERMUTED (scan2)
__global__ void prep_k(const float* __restrict__ W1ih, const float* __restrict__ W1hh,
                       const float* __restrict__ W2ih, const float* __restrict__ W2hh,
                       const float* __restrict__ Wo,
                       ush* __restrict__ W1P, ush* __restrict__ W2T,
                       ush* __restrict__ WoB) {
    int i = blockIdx.x * blockDim.x + threadIdx.x;
    if (i < K1 * G4) {
        int k = i / G4, jn = i % G4;
        int r = jn / 400, q = jn % 400, g = q / 100, cl = q % 100;
        int j = g * 400 + r * 100 + cl;
        float v = (k < 63) ? W1ih[j * 63 + k] : W1hh[j * CS + (k - 63)];
        W1P[i] = f2b(v);
    }
    if (i < 863 * G4) {
        int k = i / G4, jj = i % G4;
        float v;
        if (k < K2) {
            v = W2ih[jj * K2 + k];
        } else {
            int r = jj / 400, q = jj % 400, g = q / 100, cl = q % 100;
            int j = g * 400 + r * 100 + cl;
            v = W2hh[j * CS + (k - K2)];
        }
        W2T[i] = f2b(v);
    }
    if (i < NP * CAT) WoB[i] = f2b(Wo[i]);
}

// ---------------------------------------------------------------- scan1: 4 blocks per batch
__global__ __launch_bounds__(1024) void scan1_k(
    const float* __restrict__ x, const float* __restrict__ onehots,
    const float* __restrict__ text_lens, const float* __restrict__ w0,
    const float* __restrict__ kap0, const float* __restrict__ h10,
    const float* __restrict__ c10, const float* __restrict__ b1,
    const float* __restrict__ Ww, const float* __restrict__ bw,
    const ush* __restrict__ W1P,
    ush* __restrict__ h1s, ush* __restrict__ wsA, float* __restrict__ outp,
    float* __restrict__ hx, unsigned* __restrict__ flg) {
    const int blk = blockIdx.x;
    const int b = blk >> 2, r = blk & 3;
    const int tid = threadIdx.x;
    __shared__ float inp[K1];          // [0:3]=x_t [3:63]=w [63:463]=h1 (full)
    __shared__ float cst[100];         // own cell slice
    __shared__ float part[20 * 400];
    __shared__ float gs[400];
    __shared__ float oh[NU * NV];
    __shared__ float biasl[400];
    __shared__ float al[NK], be[NK], kap[NK], phi[NU + 1], bwl[3 * NK];
    __shared__ float tl;

    for (int i = tid; i < NU * NV; i += 1024) oh[i] = onehots[b * NU * NV + i];
    if (tid < 400) {
        int g = tid / 100, cl = tid % 100;
        biasl[tid] = b1[g * 400 + r * 100 + cl];
        inp[63 + tid] = h10[b * CS + tid];
    }
    if (tid >= 512 && tid < 612) cst[tid - 512] = c10[b * CS + r * 100 + (tid - 512)];
    if (tid >= 640 && tid < 700) inp[3 + tid - 640] = w0[b * NV + (tid - 640)];
    if (tid >= 704 && tid < 714) kap[tid - 704] = kap0[b * NK + (tid - 704)];
    if (tid >= 736 && tid < 766) bwl[tid - 736] = bw[tid - 736];
    if (tid >= 768 && tid < 771) inp[tid - 768] = x[(b * NT + 0) * 3 + (tid - 768)];
    if (tid == 800) tl = text_lens[b];
    __syncthreads();

    const int ks = tid / 50;                   // 0..19 (tid<1000)
    const int jt = tid - ks * 50;              // 0..49
    const int k0 = (ks * K1) / 20, k1e = ((ks + 1) * K1) / 20;
    const ush* wcol = W1P + (size_t)r * 400 + jt * 8 + (size_t)k0 * G4;
    float* pprow = part + ks * 400 + jt;

    for (int t = 0; t < NT; ++t) {
        if (tid < 1000) {
            float acc[8] = {0.f, 0.f, 0.f, 0.f, 0.f, 0.f, 0.f, 0.f};
            const ush* wp = wcol;
            for (int k = k0; k < k1e; ++k, wp += G4) {
                float a = inp[k];
                uint4 wv = *(const uint4*)wp;
                acc[0] = fmaf(a, blo(wv.x), acc[0]); acc[1] = fmaf(a, bhi(wv.x), acc[1]);
                acc[2] = fmaf(a, blo(wv.y), acc[2]); acc[3] = fmaf(a, bhi(wv.y), acc[3]);
                acc[4] = fmaf(a, blo(wv.z), acc[4]); acc[5] = fmaf(a, bhi(wv.z), acc[5]);
                acc[6] = fmaf(a, blo(wv.w), acc[6]); acc[7] = fmaf(a, bhi(wv.w), acc[7]);
            }
            #pragma unroll
            for (int rr = 0; rr < 8; ++rr) pprow[rr * 50] = acc[rr];
        }
        __syncthreads();
        if (tid < 400) {                        // reduce 20 k-slices
            const float* pb = part + (tid & 7) * 50 + (tid >> 3);
            float s = 0.f;
            #pragma unroll
            for (int kk = 0; kk < 20; ++kk) s += pb[kk * 400];
            gs[tid] = s;
        }
        __syncthreads();
        if (tid < 100) {                        // cell update (own 100 cells)
            float gi = gs[tid] + biasl[tid];
            float gf = gs[100 + tid] + biasl[100 + tid];
            float gg = gs[200 + tid] + biasl[200 + tid];
            float go = gs[300 + tid] + biasl[300 + tid];
            float c = sigm(gf) * cst[tid] + sigm(gi) * tanhf(gg);
            float h = sigm(go) * tanhf(c);
            cst[tid] = c;
            int ci = r * 100 + tid;
            inp[63 + ci] = h;
            __hip_atomic_store(&hx[(size_t)(t & 1) * (NB * CS) + b * CS + ci], h,
                               __ATOMIC_RELAXED, __HIP_MEMORY_SCOPE_AGENT);
            h1s[((size_t)t * NB + b) * CS + ci] = f2b(h);
        }
        asm volatile("s_waitcnt vmcnt(0)" ::: "memory");
        __syncthreads();
        if (tid == 0) {
            __hip_atomic_fetch_add(&flg[b], 1u, __ATOMIC_RELAXED, __HIP_MEMORY_SCOPE_AGENT);
            unsigned tgt = 4u * (unsigned)(t + 1);
            while (__hip_atomic_load(&flg[b], __ATOMIC_RELAXED, __HIP_MEMORY_SCOPE_AGENT) < tgt)
                __builtin_amdgcn_s_sleep(1);
        }
        __syncthreads();
        if (tid < 400 && (tid / 100) != r) {    // pull peer h slices
            inp[63 + tid] = __hip_atomic_load(&hx[(size_t)(t & 1) * (NB * CS) + b * CS + tid],
                                              __ATOMIC_RELAXED, __HIP_MEMORY_SCOPE_AGENT);
        }
        __syncthreads();
        // attention p (redundant in all 4 blocks)
        if (tid < 480) {
            int g = tid >> 4, l = tid & 15;
            float s = 0.f;
            const float* wr = Ww + g * CS;
            for (int k = l; k < CS; k += 16) s += inp[63 + k] * wr[k];
            s += __shfl_down(s, 8, 16);
            s += __shfl_down(s, 4, 16);
            s += __shfl_down(s, 2, 16);
            s += __shfl_down(s, 1, 16);
            if (l == 0) {
                float pv = expf(s + bwl[g]);
                if (g < NK) al[g] = pv;
                else if (g < 2 * NK) be[g - NK] = pv;
                else kap[g - 2 * NK] += pv;
            }
        }
        __syncthreads();
        if (tid <= NU) {
            float u = (float)tid, s = 0.f;
            #pragma unroll
            for (int k = 0; k < NK; ++k) { float d = kap[k] - u; s += al[k] * expf(-be[k] * d * d); }
            phi[tid] = s * (80.f / tl);
        }
        __syncthreads();
        if (tid < NV) {
            float s = 0.f;
            for (int u = 0; u < NU; ++u) s += phi[u] * oh[u * NV + tid];
            inp[3 + tid] = s;
            if (r == 0) wsA[((size_t)t * NB + b) * NV + tid] = f2b(s);
        } else if (tid >= 64 && tid < 67) {
            if (t + 1 < NT) inp[tid - 64] = x[(b * NT + t + 1) * 3 + (tid - 64)];
        }
        __syncthreads();
    }
    if (tid < 100) outp[OFF_C1 + b * CS + r * 100 + tid] = cst[tid];
    if (r == 0) {
        if (tid < 400) outp[OFF_H1 + b * CS + tid] = inp[63 + tid];
        if (tid >= 512 && tid < 572) outp[OFF_WOLD + b * NV + (tid - 512)] = inp[3 + tid - 512];
        if (tid >= 576 && tid < 586) outp[OFF_KAP + b * NK + (tid - 576)] = kap[tid - 576];
        if (tid >= 640 && tid <= 640 + NU) outp[OFF_PHI + b * (NU + 1) + (tid - 640)] = phi[tid - 640];
    }
}

// ---------------------------------------------------------------- gemmZ (unchanged)
__global__ __launch_bounds__(256) void gemmZ_k(
    const float* __restrict__ x, const ush* __restrict__ wsA, const ush* __restrict__ h1s,
    const ush* __restrict__ W2T, const float* __restrict__ b2,
    ush* __restrict__ Z, int n0) {
    __shared__ float As[32][64];
    __shared__ float Bs[32][64];
    const int tid = threadIdx.x;
    const int jt = blockIdx.x * 64;
    const int nt = blockIdx.y * 64;
    const int tx = tid & 15, ty = tid >> 4;
    float acc[4][4] = {};
    for (int k0 = 0; k0 < K2; k0 += 32) {
        {
            int n = tid >> 2, kk = (tid & 3) * 8;
            int np = n0 + nt + n;
            int bb = np & 63, tt = np >> 6;
            #pragma unroll
            for (int rr = 0; rr < 8; ++rr) {
                int k = k0 + kk + rr;
                float v = 0.f;
                if (k < K2) {
                    if (k < 3) v = x[(bb * NT + tt) * 3 + k];
                    else if (k < 63) v = b2f(wsA[((size_t)tt * NB + bb) * NV + (k - 3)]);
                    else v = b2f(h1s[((size_t)tt * NB + bb) * CS + (k - 63)]);
                }
                As[kk + rr][n] = v;
            }
        }
        {
            int kk = tid >> 3, j8 = (tid & 7) * 8;
            int k = k0 + kk;
            if (k < K2) {
                uint4 wv = *(const uint4*)(W2T + (size_t)k * G4 + jt + j8);
                Bs[kk][j8 + 0] = blo(wv.x); Bs[kk][j8 + 1] = bhi(wv.x);
                Bs[kk][j8 + 2] = blo(wv.y); Bs[kk][j8 + 3] = bhi(wv.y);
                Bs[kk][j8 + 4] = blo(wv.z); Bs[kk][j8 + 5] = bhi(wv.z);
                Bs[kk][j8 + 6] = blo(wv.w); Bs[kk][j8 + 7] = bhi(wv.w);
            } else {
                #pragma unroll
                for (int rr = 0; rr < 8; ++rr) Bs[kk][j8 + rr] = 0.f;
            }
        }
        __syncthreads();
        #pragma unroll
        for (int kk = 0; kk < 32; ++kk) {
            float a0 = As[kk][ty * 4 + 0], a1 = As[kk][ty * 4 + 1];
            float a2 = As[kk][ty * 4 + 2], a3 = As[kk][ty * 4 + 3];
            float c0 = Bs[kk][tx * 4 + 0], c1 = Bs[kk][tx * 4 + 1];
            float c2 = Bs[kk][tx * 4 + 2], c3 = Bs[kk][tx * 4 + 3];
            acc[0][0] = fmaf(a0, c0, acc[0][0]); acc[0][1] = fmaf(a0, c1, acc[0][1]);
            acc[0][2] = fmaf(a0, c2, acc[0][2]); acc[0][3] = fmaf(a0, c3, acc[0][3]);
            acc[1][0] = fmaf(a1, c0, acc[1][0]); acc[1][1] = fmaf(a1, c1, acc[1][1]);
            acc[1][2] = fmaf(a1, c2, acc[1][2]); acc[1][3] = fmaf(a1, c3, acc[1][3]);
            acc[2][0] = fmaf(a2, c0, acc[2][0]); acc[2][1] = fmaf(a2, c1, acc[2][1]);
            acc[2][2] = fmaf(a2, c2, acc[2][2]); acc[2][3] = fmaf(a2, c3, acc[2][3]);
            acc[3][0] = fmaf(a3, c0, acc[3][0]); acc[3][1] = fmaf(a3, c1, acc[3][1]);
            acc[3][2] = fmaf(a3, c2, acc[3][2]); acc[3][3] = fmaf(a3, c3, acc[3][3]);
        }
        __syncthreads();
    }
    #pragma unroll
    for (int rr = 0; rr < 4; ++rr) {
        int n = nt + ty * 4 + rr;
        #pragma unroll
        for (int c = 0; c < 4; ++c) {
            int j = jt + tx * 4 + c;
            Z[(size_t)n * G4 + j] = f2b(acc[rr][c] + b2[j]);
        }
    }
}

// ---------------------------------------------------------------- scan2: 4 blocks per batch
__global__ __launch_bounds__(1024) void scan2_k(
    const ush* __restrict__ Z, const ush* __restrict__ W2P, const ush* __restrict__ WoB,
    const ush* __restrict__ h1s, const float* __restrict__ bo,
    const float* __restrict__ h20, const float* __restrict__ c20,
    float* __restrict__ h2st, float* __restrict__ c2st,
    float* __restrict__ outp, float* __restrict__ hx2, unsigned* __restrict__ flg2,
    int t0, int first, int last) {
    const int blk = blockIdx.x;
    const int b = blk >> 2, r = blk & 3;
    const int tid = threadIdx.x;
    __shared__ float h2l[CS], c2l[100], h1f[CS];
    __shared__ float part[20 * 400];
    __shared__ float gs[400];
    __shared__ float ps[32];
    const int jlo = r * 30, jcnt = (r == 3) ? 31 : 30;

    if (tid < 400) h2l[tid] = first ? h20[b * CS + tid] : h2st[b * CS + tid];
    if (tid >= 512 && tid < 612)
        c2l[tid - 512] = first ? c20[b * CS + r * 100 + (tid - 512)]
                               : c2st[b * CS + r * 100 + (tid - 512)];
    __syncthreads();

    const int ks = tid / 50;                 // 0..19 (tid<1000), k-slice of 20
    const int jt = tid - ks * 50;
    const int k0 = ks * 20;
    const ush* wcol = W2P + (size_t)(K2 + k0) * G4 + r * 400 + jt * 8;
    float* pprow = part + ks * 400 + jt;

    for (int ti = 0; ti < CHUNK; ++ti) {
        const int gt = t0 + ti;
        if (tid < 1000) {
            float acc[8] = {0.f, 0.f, 0.f, 0.f, 0.f, 0.f, 0.f, 0.f};
            const ush* wp = wcol;
            #pragma unroll 4
            for (int kk = 0; kk < 20; ++kk, wp += G4) {
                float a = h2l[k0 + kk];
                uint4 wv = *(const uint4*)wp;
                acc[0] = fmaf(a, blo(wv.x), acc[0]); acc[1] = fmaf(a, bhi(wv.x), acc[1]);
                acc[2] = fmaf(a, blo(wv.y), acc[2]); acc[3] = fmaf(a, bhi(wv.y), acc[3]);
                acc[4] = fmaf(a, blo(wv.z), acc[4]); acc[5] = fmaf(a, bhi(wv.z), acc[5]);
                acc[6] = fmaf(a, blo(wv.w), acc[6]); acc[7] = fmaf(a, bhi(wv.w), acc[7]);
            }
            #pragma unroll
            for (int rr = 0; rr < 8; ++rr) pprow[rr * 50] = acc[rr];
        } else {
            for (int k = tid - 1000; k < 400; k += 24)
                h1f[k] = b2f(h1s[((size_t)gt * NB + b) * CS + k]);
        }
        __syncthreads();
        if (tid < 400) {
            const float* pb = part + (tid & 7) * 50 + (tid >> 3);
            float s = 0.f;
            #pragma unroll
            for (int kk = 0; kk < 20; ++kk) s += pb[kk * 400];
            gs[tid] = s;
        }
        __syncthreads();
        if (tid < 100) {
            const size_t zb = ((size_t)ti * NB + b) * G4;
            int cbase = r * 100 + tid;
            float gi = gs[tid]       + b2f(Z[zb + 0 * CS + cbase]);
            float gf = gs[100 + tid] + b2f(Z[zb + 1 * CS + cbase]);
            float gg = gs[200 + tid] + b2f(Z[zb + 2 * CS + cbase]);
            float go = gs[300 + tid] + b2f(Z[zb + 3 * CS + cbase]);
            float c = sigm(gf) * c2l[tid] + sigm(gi) * tanhf(gg);
            float h = sigm(go) * tanhf(c);
            c2l[tid] = c;
            h2l[cbase] = h;
            __hip_atomic_store(&hx2[(size_t)(gt & 1) * (NB * CS) + b * CS + cbase], h,
                               __ATOMIC_RELAXED, __HIP_MEMORY_SCOPE_AGENT);
        }
        asm volatile("s_waitcnt vmcnt(0)" ::: "memory");
        __syncthreads();
        if (tid == 0) {
            __hip_atomic_fetch_add(&flg2[b], 1u, __ATOMIC_RELAXED, __HIP_MEMORY_SCOPE_AGENT);
            unsigned tgt = 4u * (unsigned)(gt + 1);
            while (__hip_atomic_load(&flg2[b], __ATOMIC_RELAXED, __HIP_MEMORY_SCOPE_AGENT) < tgt)
                __builtin_amdgcn_s_sleep(1);
        }
        __syncthreads();
        if (tid < 400 && (tid / 100) != r) {
            h2l[tid] = __hip_atomic_load(&hx2[(size_t)(gt & 1) * (NB * CS) + b * CS + tid],
                                         __ATOMIC_RELAXED, __HIP_MEMORY_SCOPE_AGENT);
        }
        __syncthreads();
        // head: own j-slice [jlo, jlo+jcnt)
        if (tid < jcnt * 8) {
            int jj = tid >> 3, l = tid & 7;
            int j = jlo + jj;
            const ush* wrow = WoB + j * CAT + l * 100;
            float s = 0.f;
            if (l < 4) {
                const float* crow = h1f + l * 100;
                #pragma unroll 10
                for (int kk = 0; kk < 100; kk += 2) {
                    unsigned wv = *(const unsigned*)(wrow + kk);
                    s = fmaf(crow[kk], blo(wv), s);
                    s = fmaf(crow[kk + 1], bhi(wv), s);
                }
            } else {
                const float* crow = h2l + (l - 4) * 100;
                #pragma unroll 10
                for (int kk = 0; kk < 100; kk += 2) {
                    unsigned wv = *(const unsigned*)(wrow + kk);
                    s = fmaf(crow[kk], blo(wv), s);
                    s = fmaf(crow[kk + 1], bhi(wv), s);
                }
            }
            s += __shfl_down(s, 4, 8);
            s += __shfl_down(s, 2, 8);
            s += __shfl_down(s, 1, 8);
            if (l == 0) ps[jj] = s + bo[j];
        }
        __syncthreads();
        {
            const size_t nt_ = (size_t)b * NT + gt;
            if (tid < jcnt) {
                int j = jlo + tid;
                float v = ps[tid];
                if (j == 120) {
                    outp[OFF_END + nt_] = sigm(v);
                } else if (j < 20) {   // only block 0 (jlo==0) reaches here
                    float mx = -1e30f;
                    #pragma unroll
                    for (int m = 0; m < NM; ++m) mx = fmaxf(mx, ps[m]);
                    float sm = 0.f;
                    #pragma unroll
                    for (int m = 0; m < NM; ++m) sm += expf(ps[m] - mx);
                    outp[OFF_W + nt_ * NM + j] = expf(v - mx) / sm;
                } else {
                    int sec = j / 20, idx = j - sec * 20;
                    float o = (sec == 5) ? tanhf(v) : v;
                    unsigned offs = (sec == 1) ? OFF_MU1 : (sec == 2) ? OFF_MU2 :
                                    (sec == 3) ? OFF_LS1 : (sec == 4) ? OFF_LS2 : OFF_RHO;
                    outp[offs + nt_ * NM + idx] = o;
                }
            }
        }
        __syncthreads();
    }
    if (tid < 100) {
        int cbase = r * 100 + tid;
        h2st[b * CS + cbase] = h2l[cbase];
        c2st[b * CS + cbase] = c2l[tid];
        if (last) {
            outp[OFF_H2 + b * CS + cbase] = h2l[cbase];
            outp[OFF_C2 + b * CS + cbase] = c2l[tid];
        }
    }
}

// ---------------------------------------------------------------- launch
extern "C" void kernel_launch(void* const* d_in, const int* in_sizes, int n_in,
                              void* d_out, int out_size, void* d_ws, size_t ws_size,
                              hipStream_t stream) {
    const float* x    = (const float*)d_in[0];
    const float* oh   = (const float*)d_in[1];
    const float* tl   = (const float*)d_in[2];
    const float* w0   = (const float*)d_in[3];
    const float* kp0  = (const float*)d_in[4];
    const float* h10  = (const float*)d_in[5];
    const float* c10  = (const float*)d_in[6];
    const float* h20  = (const float*)d_in[7];
    const float* c20  = (const float*)d_in[8];
    const float* W1ih = (const float*)d_in[9];
    const float* W1hh = (const float*)d_in[10];
    const float* b1   = (const float*)d_in[11];
    const float* Ww   = (const float*)d_in[12];
    const float* bw   = (const float*)d_in[13];
    const float* W2ih = (const float*)d_in[14];
    const float* W2hh = (const float*)d_in[15];
    const float* b2   = (const float*)d_in[16];
    const float* Wo   = (const float*)d_in[17];
    const float* bo   = (const float*)d_in[18];
    float* outp = (float*)d_out;

    char* p = (char*)d_ws;
    auto alloc = [&](size_t bytes) { char* r = p; p += (bytes + 255) & ~(size_t)255; return r; };
    ush*   W1P  = (ush*)  alloc((size_t)K1 * G4 * 2);
    ush*   W2T  = (ush*)  alloc((size_t)863 * G4 * 2);
    ush*   WoB  = (ush*)  alloc((size_t)NP * CAT * 2);
    ush*   h1s  = (ush*)  alloc((size_t)NT * NB * CS * 2);
    ush*   wsA  = (ush*)  alloc((size_t)NT * NB * NV * 2);
    ush*   Zb   = (ush*)  alloc((size_t)CHUNK * NB * G4 * 2);
    float* h2st = (float*)alloc((size_t)NB * CS * 4);
    float* c2st = (float*)alloc((size_t)NB * CS * 4);
    float* hx1  = (float*)alloc((size_t)2 * NB * CS * 4);
    float* hx2  = (float*)alloc((size_t)2 * NB * CS * 4);
    unsigned* flg = (unsigned*)alloc(512);   // [0:64)=scan1, [64:128)=scan2

    hipMemsetAsync(flg, 0, 512, stream);
    prep_k<<<(863 * G4 + 255) / 256, 256, 0, stream>>>(W1ih, W1hh, W2ih, W2hh, Wo,
                                                       W1P, W2T, WoB);
    scan1_k<<<4 * NB, 1024, 0, stream>>>(x, oh, tl, w0, kp0, h10, c10, b1, Ww, bw, W1P,
                                         h1s, wsA, outp, hx1, flg);
    for (int c = 0; c < NCHUNK; ++c) {
        gemmZ_k<<<dim3(G4 / 64, CHUNK * NB / 64), 256, 0, stream>>>(
            x, wsA, h1s, W2T, b2, Zb, c * CHUNK * NB);
        scan2_k<<<4 * NB, 1024, 0, stream>>>(
            Zb, W2T, WoB, h1s, bo, h20, c20, h2st, c2st, outp, hx2, flg + 64,
            c * CHUNK, c == 0, c == NCHUNK - 1);
    }
}